// Round 12
// baseline (382.816 us; speedup 1.0000x reference)
//
#include <hip/hip_runtime.h>
#include <math.h>

#define L_MAX 3
#define RCUT 5.0f
#define NB 8
#define NCH 16
#define KDIM 64
#define LMDIM 16   // sum (2l+1), l=0..3
#define GSTRIDE 40 // per-edge geometry floats: sh[16], b[8], R[16]

// feats layout is K-MAJOR: feats[atom*1024 + k*16 + lm]  (lm fastest)
// T layout: T[atom*256 + sp*64 + lm*4 + n]  (species-factored first-MP accumulator)

// ---------------- compile-time Clebsch-Gordan (mirrors reference _real_cg) ----------------
struct CD { double re; double im; };
struct UMat { CD m[7][7]; };
struct CGT { float v[7][7][7]; };

constexpr double cfact(int n){ double r=1.0; for(int i=2;i<=n;++i) r*=(double)i; return r; }
constexpr double cfabs(double x){ return x<0.0 ? -x : x; }
constexpr double csqrt_(double x){
  if (x<=0.0) return 0.0;
  double g = x>1.0 ? x : 1.0;
  for (int i=0;i<100;++i) g = 0.5*(g + x/g);
  return g;
}
constexpr double clebsch(int j1,int m1,int j2,int m2,int J,int M){
  if (m1+m2!=M) return 0.0;
  int ad = j1-j2; if (ad<0) ad=-ad;
  if (J<ad || J>j1+j2) return 0.0;
  double pref = csqrt_((2.0*J+1.0)*cfact(J+j1-j2)*cfact(J-j1+j2)*cfact(j1+j2-J)/cfact(j1+j2+J+1));
  pref *= csqrt_(cfact(J+M)*cfact(J-M)*cfact(j1-m1)*cfact(j1+m1)*cfact(j2-m2)*cfact(j2+m2));
  double s=0.0;
  for (int k=0;k<=j1+j2-J;++k){
    int d0=k,d1=j1+j2-J-k,d2=j1-m1-k,d3=j2+m2-k,d4=J-j2+m1+k,d5=J-j1-m2+k;
    if (d0<0||d1<0||d2<0||d3<0||d4<0||d5<0) continue;
    double den = cfact(d0)*cfact(d1)*cfact(d2)*cfact(d3)*cfact(d4)*cfact(d5);
    s += ((k&1)? -1.0:1.0)/den;
  }
  return pref*s;
}
constexpr UMat u_real(int l){
  UMat U{};
  U.m[l][l] = CD{1.0, 0.0};
  double is2 = csqrt_(0.5);
  for (int mm=1; mm<=l; ++mm){
    double sgn = (mm&1)? -1.0: 1.0;
    U.m[l+mm][l+mm] = CD{sgn*is2, 0.0};
    U.m[l+mm][l-mm] = CD{is2, 0.0};
    U.m[l-mm][l-mm] = CD{0.0, is2};
    U.m[l-mm][l+mm] = CD{0.0, -sgn*is2};
  }
  return U;
}
constexpr CGT real_cg(int l1,int l2,int L){
  double Cc[7][7][7] = {};
  for (int m1=-l1;m1<=l1;++m1)
    for (int m2=-l2;m2<=l2;++m2){
      int M=m1+m2;
      if (M>=-L && M<=L) Cc[l1+m1][l2+m2][L+M] = clebsch(l1,m1,l2,m2,L,M);
    }
  UMat U1=u_real(l1), U2=u_real(l2), U3=u_real(L);
  double Tre[7][7][7]={}, Tim[7][7][7]={};
  for (int a=0;a<2*l1+1;++a)
   for (int m=0;m<2*l1+1;++m){
     CD u1=U1.m[a][m];
     if (u1.re==0.0 && u1.im==0.0) continue;
     for (int b=0;b<2*l2+1;++b)
      for (int n=0;n<2*l2+1;++n){
        CD u2=U2.m[b][n];
        if (u2.re==0.0 && u2.im==0.0) continue;
        CD u12 = CD{u1.re*u2.re-u1.im*u2.im, u1.re*u2.im+u1.im*u2.re};
        for (int c=0;c<2*L+1;++c)
         for (int o=0;o<2*L+1;++o){
           CD u3=U3.m[c][o];
           if (u3.re==0.0 && u3.im==0.0) continue;
           double cc=Cc[m][n][o];
           if (cc==0.0) continue;
           double tr = u12.re*u3.re + u12.im*u3.im;   // u12 * conj(u3)
           double ti = u12.im*u3.re - u12.re*u3.im;
           Tre[a][b][c] += tr*cc;
           Tim[a][b][c] += ti*cc;
         }
      }
   }
  double sre=0.0, sim=0.0;
  for (int a=0;a<2*l1+1;++a) for (int b=0;b<2*l2+1;++b) for (int c=0;c<2*L+1;++c){
    sre += cfabs(Tre[a][b][c]); sim += cfabs(Tim[a][b][c]);
  }
  CGT out{};
  bool ure = (sre>=sim);
  for (int a=0;a<2*l1+1;++a) for (int b=0;b<2*l2+1;++b) for (int c=0;c<2*L+1;++c)
    out.v[a][b][c] = (float)(ure? Tre[a][b][c] : Tim[a][b][c]);
  return out;
}

// A[M][j] = sum_i Cflat[M*16+j][i]*sh[i], MP_SCALING 0.5 folded in (second MP only).
struct alignas(64) CFlat { float v[256][16]; };
constexpr CFlat build_cflat(){
  CFlat o{};
  for (int l1=0;l1<=3;++l1)
   for (int l2=0;l2<=3;++l2){
     int lo = l1>l2 ? l1-l2 : l2-l1;
     int hi = (l1+l2<3)? l1+l2 : 3;
     for (int L=lo; L<=hi; ++L){
       CGT cg = real_cg(l1,l2,L);
       for (int i=0;i<2*l1+1;++i)
        for (int j=0;j<2*l2+1;++j)
         for (int m=0;m<2*L+1;++m){
           o.v[(L*L+m)*16 + (l2*l2+j)][l1*l1+i] += 0.5f*cg.v[i][j][m];
         }
     }
   }
  return o;
}
__device__ const CFlat CFLAT = build_cflat();

// symmetrized dense CG for f (x) f tensor product (NO scaling): only i<=j iterated.
struct CSym { float v[16][16][16]; };
constexpr CSym build_csym(){
  CSym o{};
  for (int l1=0;l1<=3;++l1)
   for (int l2=0;l2<=3;++l2){
     int lo = l1>l2 ? l1-l2 : l2-l1;
     int hi = (l1+l2<3)? l1+l2 : 3;
     for (int L=lo; L<=hi; ++L){
       CGT cg = real_cg(l1,l2,L);
       for (int i=0;i<2*l1+1;++i)
        for (int j=0;j<2*l2+1;++j)
         for (int m=0;m<2*L+1;++m)
           o.v[L*L+m][l1*l1+i][l2*l2+j] += cg.v[i][j][m];
     }
   }
  for (int M=0;M<16;++M)
   for (int i=0;i<16;++i)
    for (int j=i+1;j<16;++j){
      o.v[M][i][j] += o.v[M][j][i];
      o.v[M][j][i] = 0.0f;
    }
  return o;
}

template<int M>
__device__ __forceinline__ float tp_row(const float* __restrict__ f){
  constexpr CSym CS = build_csym();
  float g = 0.0f;
  #pragma unroll
  for (int i=0;i<16;++i)
  #pragma unroll
  for (int j=i;j<16;++j){
    float c = CS.v[M][i][j];
    if (c != 0.0f) g += c * f[i] * f[j];
  }
  return g;
}

template<int l>
__device__ __forceinline__ float inv_term(const float* m){
  constexpr CGT cg = real_cg(l,l,0);
  float a=0.0f;
  #pragma unroll
  for (int i=0;i<2*l+1;++i)
  #pragma unroll
  for (int j=0;j<2*l+1;++j){
    float c = cg.v[i][j][0];
    if (c != 0.0f) a += c*m[l*l+i]*m[l*l+j];
  }
  return a;
}

// ---------------- geometry ----------------
__device__ __forceinline__ void compute_sh(float x, float y, float z, float* sh){
  sh[0]  = 0.28209479177387814f;
  sh[1]  = 0.4886025119029199f*y;
  sh[2]  = 0.4886025119029199f*z;
  sh[3]  = 0.4886025119029199f*x;
  sh[4]  = 1.0925484305920792f*x*y;
  sh[5]  = 1.0925484305920792f*y*z;
  sh[6]  = 0.31539156525252005f*(3.0f*z*z-1.0f);
  sh[7]  = 1.0925484305920792f*x*z;
  sh[8]  = 0.5462742152960396f*(x*x-y*y);
  sh[9]  = 0.5900435899266435f*y*(3.0f*x*x-y*y);
  sh[10] = 2.890611442640554f*x*y*z;
  sh[11] = 0.4570457994644658f*y*(5.0f*z*z-1.0f);
  sh[12] = 0.3731763325901154f*z*(5.0f*z*z-3.0f);
  sh[13] = 0.4570457994644658f*x*(5.0f*z*z-1.0f);
  sh[14] = 1.445305721320277f*z*(x*x-y*y);
  sh[15] = 0.5900435899266435f*x*(x*x-3.0f*y*y);
}

// ---------------- CSR build with distance filter ----------------
__global__ __launch_bounds__(256) void k_hist_d(
    const float* __restrict__ pos, const int* __restrict__ senders,
    const int* __restrict__ recv, int* __restrict__ counts, int E)
{
  int e = blockIdx.x*256 + threadIdx.x;
  if (e >= E) return;
  int s = senders[e], r = recv[e];
  float dx = pos[r*3+0]-pos[s*3+0];
  float dy = pos[r*3+1]-pos[s*3+1];
  float dz = pos[r*3+2]-pos[s*3+2];
  float d  = sqrtf(dx*dx+dy*dy+dz*dz + 1e-12f);
  if (d < RCUT) atomicAdd(&counts[r], 1);
}

__global__ __launch_bounds__(256) void k_scan1(const int* __restrict__ counts,
                                               int* __restrict__ offsets,
                                               int* __restrict__ bsum, int N){
  __shared__ int buf[256];
  int i = blockIdx.x*256 + threadIdx.x;
  int v = (i<N)? counts[i] : 0;
  buf[threadIdx.x] = v;
  __syncthreads();
  #pragma unroll
  for (int o=1;o<256;o<<=1){
    int t = (threadIdx.x>=o)? buf[threadIdx.x-o] : 0;
    __syncthreads();
    buf[threadIdx.x] += t;
    __syncthreads();
  }
  if (i<N) offsets[i] = buf[threadIdx.x] - v;      // local exclusive
  if (threadIdx.x==255) bsum[blockIdx.x] = buf[255];
}

__global__ __launch_bounds__(256) void k_scan2(const int* __restrict__ bsum,
                                               int* __restrict__ bbase, int SB){
  __shared__ int buf[256];
  int v = (threadIdx.x<SB)? bsum[threadIdx.x] : 0;
  buf[threadIdx.x] = v;
  __syncthreads();
  #pragma unroll
  for (int o=1;o<256;o<<=1){
    int t = (threadIdx.x>=o)? buf[threadIdx.x-o] : 0;
    __syncthreads();
    buf[threadIdx.x] += t;
    __syncthreads();
  }
  if (threadIdx.x<SB) bbase[threadIdx.x] = buf[threadIdx.x] - v;
}

__global__ __launch_bounds__(256) void k_scan3(int* __restrict__ offsets,
                                               const int* __restrict__ bbase, int N){
  int i = blockIdx.x*256 + threadIdx.x;
  if (i<N) offsets[i] += bbase[blockIdx.x];
}

// thread per edge: filter, claim slot, precompute geometry into bucket-ordered arrays,
// and accumulate the species-factored first-MP tensor T[r][sp][lm][n] (edge-parallel).
__global__ __launch_bounds__(256) void k_geom(
    const float* __restrict__ pos, const float* __restrict__ Winv,
    const int* __restrict__ species,
    const int* __restrict__ senders, const int* __restrict__ recv,
    const int* __restrict__ offsets, int* __restrict__ cursor,
    int* __restrict__ bucket_s, float* __restrict__ geomArr,
    float* __restrict__ T, int E)
{
  int e = blockIdx.x*256 + threadIdx.x;
  if (e >= E) return;
  int s = senders[e], r = recv[e];
  float dx = pos[r*3+0]-pos[s*3+0];
  float dy = pos[r*3+1]-pos[s*3+1];
  float dz = pos[r*3+2]-pos[s*3+2];
  float d  = sqrtf(dx*dx+dy*dy+dz*dz + 1e-12f);
  if (d >= RCUT) return;
  int p = atomicAdd(&cursor[r], 1);
  int slot = offsets[r] + p;
  float inv_d = 1.0f/d;
  float sh[16];
  compute_sh(dx*inv_d, dy*inv_d, dz*inv_d, sh);
  float fc = 0.5f*(cosf(d*(3.14159265358979323846f/RCUT))+1.0f);
  float b[8];
  #pragma unroll
  for (int q=0;q<NB;++q){
    float t = (d - (float)((double)q*(5.0/7.0))) * 1.6f;  // sigma=0.625
    b[q] = expf(-0.5f*t*t)*fc;
  }
  float R[4][4];
  float* g = geomArr + (size_t)slot*GSTRIDE;
  #pragma unroll
  for (int i=0;i<16;++i) g[i] = sh[i];
  #pragma unroll
  for (int q=0;q<8;++q) g[16+q] = b[q];
  #pragma unroll
  for (int l=0;l<4;++l)
    #pragma unroll
    for (int n=0;n<4;++n){
      float acc=0.0f;
      #pragma unroll
      for (int q=0;q<NB;++q) acc += b[q]*Winv[l*32+q*4+n];
      R[l][n]=acc;
      g[24+l*4+n] = acc;
    }
  int spec = species[s];
  bucket_s[slot] = s | (spec<<16);   // N=10000 < 2^16
  // edge-parallel first MP: T[r][spec][lm][n] += sh[lm]*R[l(lm)][n]
  float* Tr = T + (size_t)r*256 + spec*64;
  #pragma unroll
  for (int lm=0; lm<16; ++lm){
    const int l = (lm==0)?0 : (lm<4)?1 : (lm<9)?2 : 3;
    #pragma unroll
    for (int n=0;n<4;++n)
      atomicAdd(&Tr[lm*4+n], sh[lm]*R[l][n]);
  }
}

// ---------------- kernel A (expand): loop-free per-atom TP from T ----------------
// f[lm] (lane n,c) = 0.5 * sum_sp emb[sp][c] * T[r][sp][lm][n]; then TP + embed, K-MAJOR out.
__global__ __launch_bounds__(256) void kA_expand(
    const float* __restrict__ emb, const int* __restrict__ species,
    const float* __restrict__ T, float* __restrict__ feats, int N)
{
  __shared__ float Ts[4][256];
  int wv = threadIdx.x>>6, lane = threadIdx.x & 63;
  int r = blockIdx.x*4 + wv;
  if (r >= N) return;
  int n = lane>>4, c = lane&15;
  // cooperative load of T[r][*]: lane t loads float4 (sp=t>>4, lm=t&15, comps n=0..3)
  const float4* T4 = (const float4*)(T + (size_t)r*256);
  ((float4*)Ts[wv])[lane] = T4[lane];
  // same-wave LDS RAW -> compiler lgkmcnt (Ts[wv] is wave-private)
  float f[16];
  #pragma unroll
  for (int lm=0; lm<16; ++lm){
    float acc = emb[0*NCH+c]*Ts[wv][0*64+lm*4+n]
              + emb[1*NCH+c]*Ts[wv][1*64+lm*4+n]
              + emb[2*NCH+c]*Ts[wv][2*64+lm*4+n]
              + emb[3*NCH+c]*Ts[wv][3*64+lm*4+n];
    f[lm] = 0.5f*acc;   // MP_SCALING
  }
  float g[16];
  g[0]=tp_row<0>(f);  g[1]=tp_row<1>(f);  g[2]=tp_row<2>(f);  g[3]=tp_row<3>(f);
  g[4]=tp_row<4>(f);  g[5]=tp_row<5>(f);  g[6]=tp_row<6>(f);  g[7]=tp_row<7>(f);
  g[8]=tp_row<8>(f);  g[9]=tp_row<9>(f);  g[10]=tp_row<10>(f); g[11]=tp_row<11>(f);
  g[12]=tp_row<12>(f); g[13]=tp_row<13>(f); g[14]=tp_row<14>(f); g[15]=tp_row<15>(f);
  float ek = emb[species[r]*NCH + c];
  float* fp = feats + (size_t)r*(LMDIM*KDIM) + lane*LMDIM;
  float4* fp4 = (float4*)fp;
  fp4[0] = make_float4((f[0]+g[0])*ek,  (f[1]+g[1])*ek,  (f[2]+g[2])*ek,  (f[3]+g[3])*ek);
  fp4[1] = make_float4((f[4]+g[4])*ek,  (f[5]+g[5])*ek,  (f[6]+g[6])*ek,  (f[7]+g[7])*ek);
  fp4[2] = make_float4((f[8]+g[8])*ek,  (f[9]+g[9])*ek,  (f[10]+g[10])*ek,(f[11]+g[11])*ek);
  fp4[3] = make_float4((f[12]+g[12])*ek,(f[13]+g[13])*ek,(f[14]+g[14])*ek,(f[15]+g[15])*ek);
}

// ---------------- kernel B: ONE-WAVE BLOCK per atom, K-MAJOR nb gather (unchanged R11) -----
__global__ __launch_bounds__(64) void kB_mp2_mlp(
    const float* __restrict__ Weq,
    const float* __restrict__ W1, const float* __restrict__ W2,
    const float* __restrict__ wl,
    const int* __restrict__ offsets, const int* __restrict__ counts,
    const int* __restrict__ bucket_s, const float* __restrict__ geomArr,
    const float* __restrict__ embedded, float* __restrict__ eatom, int N)
{
  __shared__ __align__(16) float Arow[256];   // 1 KB/block
  int r = blockIdx.x;
  if (r >= N) return;
  int k = threadIdx.x;
  int off = offsets[r], cnt = counts[r];
  float Wq[4][8];
  #pragma unroll
  for (int L=0;L<4;++L)
    #pragma unroll
    for (int q=0;q<8;++q)
      Wq[L][q] = Weq[L*(NB*KDIM) + q*KDIM + k];
  float m[16];
  #pragma unroll
  for (int i=0;i<16;++i) m[i]=0.0f;

  float4 nb0c{}, nb1c{}, nb2c{}, nb3c{};
  {
    int pk0 = (cnt>0)? bucket_s[off] : 0;
    const float4* np0 = (const float4*)(embedded + (size_t)(pk0 & 0xFFFF)*(LMDIM*KDIM) + k*LMDIM);
    if (cnt>0){ nb0c=np0[0]; nb1c=np0[1]; nb2c=np0[2]; nb3c=np0[3]; }
  }
  for (int j=0; j<cnt; ++j){
    bool hn = (j+1<cnt);
    int pk_n = hn ? bucket_s[off+j+1] : 0;
    const float4* npn = (const float4*)(embedded + (size_t)(pk_n & 0xFFFF)*(LMDIM*KDIM) + k*LMDIM);
    float4 nb0n{}, nb1n{}, nb2n{}, nb3n{};
    if (hn){ nb0n=npn[0]; nb1n=npn[1]; nb2n=npn[2]; nb3n=npn[3]; }

    const float* gm = geomArr + (size_t)(off+j)*GSTRIDE;
    float4 s0 = *(const float4*)(gm+0);
    float4 s1 = *(const float4*)(gm+4);
    float4 s2 = *(const float4*)(gm+8);
    float4 s3 = *(const float4*)(gm+12);
    float4 b0 = *(const float4*)(gm+16);
    float4 b1 = *(const float4*)(gm+20);
    float sh[16] = {s0.x,s0.y,s0.z,s0.w, s1.x,s1.y,s1.z,s1.w,
                    s2.x,s2.y,s2.z,s2.w, s3.x,s3.y,s3.z,s3.w};
    float b[8] = {b0.x,b0.y,b0.z,b0.w, b1.x,b1.y,b1.z,b1.w};
    float Req[4];
    #pragma unroll
    for (int L=0;L<4;++L){
      float acc=0.0f;
      #pragma unroll
      for (int q=0;q<8;++q) acc += b[q]*Wq[L][q];
      Req[L]=acc;
    }
    #pragma unroll
    for (int q=0;q<4;++q){
      int ent = q*64 + k;
      const float4* c4 = (const float4*)CFLAT.v[ent];
      float4 c0=c4[0], c1=c4[1], c2=c4[2], c3=c4[3];
      float acc = c0.x*sh[0]+c0.y*sh[1]+c0.z*sh[2]+c0.w*sh[3]
                + c1.x*sh[4]+c1.y*sh[5]+c1.z*sh[6]+c1.w*sh[7]
                + c2.x*sh[8]+c2.y*sh[9]+c2.z*sh[10]+c2.w*sh[11]
                + c3.x*sh[12]+c3.y*sh[13]+c3.z*sh[14]+c3.w*sh[15];
      Arow[ent] = acc;
    }
    float nb_c[16] = {nb0c.x,nb0c.y,nb0c.z,nb0c.w, nb1c.x,nb1c.y,nb1c.z,nb1c.w,
                      nb2c.x,nb2c.y,nb2c.z,nb2c.w, nb3c.x,nb3c.y,nb3c.z,nb3c.w};
    #pragma unroll
    for (int M=0;M<16;++M){
      const int L = (M==0)?0 : (M<4)?1 : (M<9)?2 : 3;
      const float4* a4 = (const float4*)(Arow + M*16);
      float4 a0=a4[0], a1=a4[1], a2=a4[2], a3=a4[3];
      float acc = a0.x*nb_c[0]+a0.y*nb_c[1]+a0.z*nb_c[2]+a0.w*nb_c[3]
                + a1.x*nb_c[4]+a1.y*nb_c[5]+a1.z*nb_c[6]+a1.w*nb_c[7]
                + a2.x*nb_c[8]+a2.y*nb_c[9]+a2.z*nb_c[10]+a2.w*nb_c[11]
                + a3.x*nb_c[12]+a3.y*nb_c[13]+a3.z*nb_c[14]+a3.w*nb_c[15];
      m[M] += acc*Req[L];
    }
    nb0c=nb0n; nb1c=nb1n; nb2c=nb2n; nb3c=nb3n;
  }

  float inv = m[0];
  inv += inv_term<0>(m);
  inv += inv_term<1>(m);
  inv += inv_term<2>(m);
  inv += inv_term<3>(m);
  Arow[k] = inv;
  float a=0.0f;
  #pragma unroll
  for (int c=0;c<64;++c) a += Arow[c]*W1[c*64+k];
  a = a / (1.0f + expf(-a));           // silu
  Arow[64+k] = a;
  float h2=0.0f;
  #pragma unroll
  for (int c=0;c<64;++c) h2 += Arow[64+c]*W2[c*64+k];
  h2 = h2 / (1.0f + expf(-h2));
  float e = h2*wl[k];
  #pragma unroll
  for (int o=32; o>0; o>>=1) e += __shfl_down(e, o);
  if (k==0) eatom[r] = e;
}

__global__ __launch_bounds__(256) void k_reduce(const float* __restrict__ eatom,
                                                float* __restrict__ out, int N){
  __shared__ float buf[256];
  float a=0.0f;
  for (int i=threadIdx.x; i<N; i+=256) a += eatom[i];
  buf[threadIdx.x]=a;
  __syncthreads();
  #pragma unroll
  for (int o=128;o>0;o>>=1){
    if (threadIdx.x<o) buf[threadIdx.x]+=buf[threadIdx.x+o];
    __syncthreads();
  }
  if (threadIdx.x==0) out[0]=buf[0];
}

// ---------------- launch ----------------
extern "C" void kernel_launch(void* const* d_in, const int* in_sizes, int n_in,
                              void* d_out, int out_size, void* d_ws, size_t ws_size,
                              hipStream_t stream)
{
  const float* pos     = (const float*)d_in[0];
  const float* emb     = (const float*)d_in[1];
  const float* Winv    = (const float*)d_in[2];
  const float* Weq     = (const float*)d_in[3];
  const float* W1      = (const float*)d_in[4];
  const float* W2      = (const float*)d_in[5];
  const float* wl      = (const float*)d_in[6];
  const int*   species = (const int*)d_in[7];
  const int*   senders = (const int*)d_in[8];
  const int*   recv    = (const int*)d_in[9];
  int N = in_sizes[7];
  int E = in_sizes[8];

  char* ws = (char*)d_ws;
  float* feats   = (float*)ws;                                   // N*1024 f32, K-MAJOR
  float* geomArr = feats + (size_t)N*(LMDIM*KDIM);               // E*GSTRIDE f32 (worst case)
  float* eatom   = geomArr + (size_t)E*GSTRIDE;                  // N f32
  int*   counts  = (int*)(eatom + N);                            // N
  int*   cursor  = counts + N;                                   // N
  float* T       = (float*)(cursor + N);                         // N*256 (memset with counts/cursor)
  int*   offsets = (int*)(T + (size_t)N*256);                    // N
  int*   bsum    = offsets + N;                                  // 256
  int*   bbase   = bsum + 256;                                   // 256
  int*   bucket_s= bbase + 256;                                  // E

  // counts, cursor, T are contiguous -> single memset (2N ints + 256N floats)
  hipMemsetAsync(counts, 0, (size_t)N*(2+256)*sizeof(int), stream);

  int ebl = (E+255)/256;
  int SB  = (N+255)/256;
  k_hist_d<<<ebl, 256, 0, stream>>>(pos, senders, recv, counts, E);
  k_scan1<<<SB, 256, 0, stream>>>(counts, offsets, bsum, N);
  k_scan2<<<1, 256, 0, stream>>>(bsum, bbase, SB);
  k_scan3<<<SB, 256, 0, stream>>>(offsets, bbase, N);
  k_geom<<<ebl, 256, 0, stream>>>(pos, Winv, species, senders, recv, offsets, cursor,
                                  bucket_s, geomArr, T, E);
  kA_expand<<<(N+3)/4, 256, 0, stream>>>(emb, species, T, feats, N);
  kB_mp2_mlp<<<N, 64, 0, stream>>>(Weq, W1, W2, wl, offsets, counts, bucket_s, geomArr,
                                   feats, eatom, N);
  k_reduce<<<1, 256, 0, stream>>>(eatom, (float*)d_out, N);
}

// Round 13
// 230.844 us; speedup vs baseline: 1.6583x; 1.6583x over previous
//
#include <hip/hip_runtime.h>
#include <math.h>

#define L_MAX 3
#define RCUT 5.0f
#define NB 8
#define NCH 16
#define KDIM 64
#define LMDIM 16   // sum (2l+1), l=0..3
#define GSTRIDE 40 // per-edge geometry floats: sh[16], b[8], R[16]

// feats layout is K-MAJOR: feats[atom*1024 + k*16 + lm]  (lm fastest)

// ---------------- compile-time Clebsch-Gordan (mirrors reference _real_cg) ----------------
struct CD { double re; double im; };
struct UMat { CD m[7][7]; };
struct CGT { float v[7][7][7]; };

constexpr double cfact(int n){ double r=1.0; for(int i=2;i<=n;++i) r*=(double)i; return r; }
constexpr double cfabs(double x){ return x<0.0 ? -x : x; }
constexpr double csqrt_(double x){
  if (x<=0.0) return 0.0;
  double g = x>1.0 ? x : 1.0;
  for (int i=0;i<100;++i) g = 0.5*(g + x/g);
  return g;
}
constexpr double clebsch(int j1,int m1,int j2,int m2,int J,int M){
  if (m1+m2!=M) return 0.0;
  int ad = j1-j2; if (ad<0) ad=-ad;
  if (J<ad || J>j1+j2) return 0.0;
  double pref = csqrt_((2.0*J+1.0)*cfact(J+j1-j2)*cfact(J-j1+j2)*cfact(j1+j2-J)/cfact(j1+j2+J+1));
  pref *= csqrt_(cfact(J+M)*cfact(J-M)*cfact(j1-m1)*cfact(j1+m1)*cfact(j2-m2)*cfact(j2+m2));
  double s=0.0;
  for (int k=0;k<=j1+j2-J;++k){
    int d0=k,d1=j1+j2-J-k,d2=j1-m1-k,d3=j2+m2-k,d4=J-j2+m1+k,d5=J-j1-m2+k;
    if (d0<0||d1<0||d2<0||d3<0||d4<0||d5<0) continue;
    double den = cfact(d0)*cfact(d1)*cfact(d2)*cfact(d3)*cfact(d4)*cfact(d5);
    s += ((k&1)? -1.0:1.0)/den;
  }
  return pref*s;
}
constexpr UMat u_real(int l){
  UMat U{};
  U.m[l][l] = CD{1.0, 0.0};
  double is2 = csqrt_(0.5);
  for (int mm=1; mm<=l; ++mm){
    double sgn = (mm&1)? -1.0: 1.0;
    U.m[l+mm][l+mm] = CD{sgn*is2, 0.0};
    U.m[l+mm][l-mm] = CD{is2, 0.0};
    U.m[l-mm][l-mm] = CD{0.0, is2};
    U.m[l-mm][l+mm] = CD{0.0, -sgn*is2};
  }
  return U;
}
constexpr CGT real_cg(int l1,int l2,int L){
  double Cc[7][7][7] = {};
  for (int m1=-l1;m1<=l1;++m1)
    for (int m2=-l2;m2<=l2;++m2){
      int M=m1+m2;
      if (M>=-L && M<=L) Cc[l1+m1][l2+m2][L+M] = clebsch(l1,m1,l2,m2,L,M);
    }
  UMat U1=u_real(l1), U2=u_real(l2), U3=u_real(L);
  double Tre[7][7][7]={}, Tim[7][7][7]={};
  for (int a=0;a<2*l1+1;++a)
   for (int m=0;m<2*l1+1;++m){
     CD u1=U1.m[a][m];
     if (u1.re==0.0 && u1.im==0.0) continue;
     for (int b=0;b<2*l2+1;++b)
      for (int n=0;n<2*l2+1;++n){
        CD u2=U2.m[b][n];
        if (u2.re==0.0 && u2.im==0.0) continue;
        CD u12 = CD{u1.re*u2.re-u1.im*u2.im, u1.re*u2.im+u1.im*u2.re};
        for (int c=0;c<2*L+1;++c)
         for (int o=0;o<2*L+1;++o){
           CD u3=U3.m[c][o];
           if (u3.re==0.0 && u3.im==0.0) continue;
           double cc=Cc[m][n][o];
           if (cc==0.0) continue;
           double tr = u12.re*u3.re + u12.im*u3.im;   // u12 * conj(u3)
           double ti = u12.im*u3.re - u12.re*u3.im;
           Tre[a][b][c] += tr*cc;
           Tim[a][b][c] += ti*cc;
         }
      }
   }
  double sre=0.0, sim=0.0;
  for (int a=0;a<2*l1+1;++a) for (int b=0;b<2*l2+1;++b) for (int c=0;c<2*L+1;++c){
    sre += cfabs(Tre[a][b][c]); sim += cfabs(Tim[a][b][c]);
  }
  CGT out{};
  bool ure = (sre>=sim);
  for (int a=0;a<2*l1+1;++a) for (int b=0;b<2*l2+1;++b) for (int c=0;c<2*L+1;++c)
    out.v[a][b][c] = (float)(ure? Tre[a][b][c] : Tim[a][b][c]);
  return out;
}

// A[M][j] = sum_i Cflat[M*16+j][i]*sh[i], MP_SCALING 0.5 folded in (second MP only).
struct alignas(64) CFlat { float v[256][16]; };
constexpr CFlat build_cflat(){
  CFlat o{};
  for (int l1=0;l1<=3;++l1)
   for (int l2=0;l2<=3;++l2){
     int lo = l1>l2 ? l1-l2 : l2-l1;
     int hi = (l1+l2<3)? l1+l2 : 3;
     for (int L=lo; L<=hi; ++L){
       CGT cg = real_cg(l1,l2,L);
       for (int i=0;i<2*l1+1;++i)
        for (int j=0;j<2*l2+1;++j)
         for (int m=0;m<2*L+1;++m){
           o.v[(L*L+m)*16 + (l2*l2+j)][l1*l1+i] += 0.5f*cg.v[i][j][m];
         }
     }
   }
  return o;
}
__device__ const CFlat CFLAT = build_cflat();

// symmetrized dense CG for f (x) f tensor product (NO scaling): only i<=j iterated.
struct CSym { float v[16][16][16]; };
constexpr CSym build_csym(){
  CSym o{};
  for (int l1=0;l1<=3;++l1)
   for (int l2=0;l2<=3;++l2){
     int lo = l1>l2 ? l1-l2 : l2-l1;
     int hi = (l1+l2<3)? l1+l2 : 3;
     for (int L=lo; L<=hi; ++L){
       CGT cg = real_cg(l1,l2,L);
       for (int i=0;i<2*l1+1;++i)
        for (int j=0;j<2*l2+1;++j)
         for (int m=0;m<2*L+1;++m)
           o.v[L*L+m][l1*l1+i][l2*l2+j] += cg.v[i][j][m];
     }
   }
  for (int M=0;M<16;++M)
   for (int i=0;i<16;++i)
    for (int j=i+1;j<16;++j){
      o.v[M][i][j] += o.v[M][j][i];
      o.v[M][j][i] = 0.0f;
    }
  return o;
}

template<int M>
__device__ __forceinline__ float tp_row(const float* __restrict__ f){
  constexpr CSym CS = build_csym();
  float g = 0.0f;
  #pragma unroll
  for (int i=0;i<16;++i)
  #pragma unroll
  for (int j=i;j<16;++j){
    float c = CS.v[M][i][j];
    if (c != 0.0f) g += c * f[i] * f[j];
  }
  return g;
}

template<int l>
__device__ __forceinline__ float inv_term(const float* m){
  constexpr CGT cg = real_cg(l,l,0);
  float a=0.0f;
  #pragma unroll
  for (int i=0;i<2*l+1;++i)
  #pragma unroll
  for (int j=0;j<2*l+1;++j){
    float c = cg.v[i][j][0];
    if (c != 0.0f) a += c*m[l*l+i]*m[l*l+j];
  }
  return a;
}

// ---------------- geometry ----------------
__device__ __forceinline__ void compute_sh(float x, float y, float z, float* sh){
  sh[0]  = 0.28209479177387814f;
  sh[1]  = 0.4886025119029199f*y;
  sh[2]  = 0.4886025119029199f*z;
  sh[3]  = 0.4886025119029199f*x;
  sh[4]  = 1.0925484305920792f*x*y;
  sh[5]  = 1.0925484305920792f*y*z;
  sh[6]  = 0.31539156525252005f*(3.0f*z*z-1.0f);
  sh[7]  = 1.0925484305920792f*x*z;
  sh[8]  = 0.5462742152960396f*(x*x-y*y);
  sh[9]  = 0.5900435899266435f*y*(3.0f*x*x-y*y);
  sh[10] = 2.890611442640554f*x*y*z;
  sh[11] = 0.4570457994644658f*y*(5.0f*z*z-1.0f);
  sh[12] = 0.3731763325901154f*z*(5.0f*z*z-3.0f);
  sh[13] = 0.4570457994644658f*x*(5.0f*z*z-1.0f);
  sh[14] = 1.445305721320277f*z*(x*x-y*y);
  sh[15] = 0.5900435899266435f*x*(x*x-3.0f*y*y);
}

// ---------------- CSR build with distance filter ----------------
__global__ __launch_bounds__(256) void k_hist_d(
    const float* __restrict__ pos, const int* __restrict__ senders,
    const int* __restrict__ recv, int* __restrict__ counts, int E)
{
  int e = blockIdx.x*256 + threadIdx.x;
  if (e >= E) return;
  int s = senders[e], r = recv[e];
  float dx = pos[r*3+0]-pos[s*3+0];
  float dy = pos[r*3+1]-pos[s*3+1];
  float dz = pos[r*3+2]-pos[s*3+2];
  float d  = sqrtf(dx*dx+dy*dy+dz*dz + 1e-12f);
  if (d < RCUT) atomicAdd(&counts[r], 1);
}

__global__ __launch_bounds__(256) void k_scan1(const int* __restrict__ counts,
                                               int* __restrict__ offsets,
                                               int* __restrict__ bsum, int N){
  __shared__ int buf[256];
  int i = blockIdx.x*256 + threadIdx.x;
  int v = (i<N)? counts[i] : 0;
  buf[threadIdx.x] = v;
  __syncthreads();
  #pragma unroll
  for (int o=1;o<256;o<<=1){
    int t = (threadIdx.x>=o)? buf[threadIdx.x-o] : 0;
    __syncthreads();
    buf[threadIdx.x] += t;
    __syncthreads();
  }
  if (i<N) offsets[i] = buf[threadIdx.x] - v;      // local exclusive
  if (threadIdx.x==255) bsum[blockIdx.x] = buf[255];
}

__global__ __launch_bounds__(256) void k_scan2(const int* __restrict__ bsum,
                                               int* __restrict__ bbase, int SB){
  __shared__ int buf[256];
  int v = (threadIdx.x<SB)? bsum[threadIdx.x] : 0;
  buf[threadIdx.x] = v;
  __syncthreads();
  #pragma unroll
  for (int o=1;o<256;o<<=1){
    int t = (threadIdx.x>=o)? buf[threadIdx.x-o] : 0;
    __syncthreads();
    buf[threadIdx.x] += t;
    __syncthreads();
  }
  if (threadIdx.x<SB) bbase[threadIdx.x] = buf[threadIdx.x] - v;
}

__global__ __launch_bounds__(256) void k_scan3(int* __restrict__ offsets,
                                               const int* __restrict__ bbase, int N){
  int i = blockIdx.x*256 + threadIdx.x;
  if (i<N) offsets[i] += bbase[blockIdx.x];
}

// thread per edge: filter, claim slot, precompute geometry into bucket-ordered arrays
__global__ __launch_bounds__(256) void k_geom(
    const float* __restrict__ pos, const float* __restrict__ Winv,
    const int* __restrict__ species,
    const int* __restrict__ senders, const int* __restrict__ recv,
    const int* __restrict__ offsets, int* __restrict__ cursor,
    int* __restrict__ bucket_s, float* __restrict__ geomArr, int E)
{
  int e = blockIdx.x*256 + threadIdx.x;
  if (e >= E) return;
  int s = senders[e], r = recv[e];
  float dx = pos[r*3+0]-pos[s*3+0];
  float dy = pos[r*3+1]-pos[s*3+1];
  float dz = pos[r*3+2]-pos[s*3+2];
  float d  = sqrtf(dx*dx+dy*dy+dz*dz + 1e-12f);
  if (d >= RCUT) return;
  int p = atomicAdd(&cursor[r], 1);
  int slot = offsets[r] + p;
  float inv_d = 1.0f/d;
  float sh[16];
  compute_sh(dx*inv_d, dy*inv_d, dz*inv_d, sh);
  float fc = 0.5f*(cosf(d*(3.14159265358979323846f/RCUT))+1.0f);
  float b[8];
  #pragma unroll
  for (int q=0;q<NB;++q){
    float t = (d - (float)((double)q*(5.0/7.0))) * 1.6f;  // sigma=0.625
    b[q] = expf(-0.5f*t*t)*fc;
  }
  float* g = geomArr + (size_t)slot*GSTRIDE;
  #pragma unroll
  for (int i=0;i<16;++i) g[i] = sh[i];
  #pragma unroll
  for (int q=0;q<8;++q) g[16+q] = b[q];
  #pragma unroll
  for (int l=0;l<4;++l)
    #pragma unroll
    for (int n=0;n<4;++n){
      float acc=0.0f;
      #pragma unroll
      for (int q=0;q<NB;++q) acc += b[q]*Winv[l*32+q*4+n];
      g[24+l*4+n] = acc;
    }
  bucket_s[slot] = s | (species[s]<<16);   // N=10000 < 2^16
}

// ---------------- kernel A: wave-per-atom species-binned streaming gather + TP ----------------
// Accumulation lane role: lm = lane>>2, n = lane&3. Per consecutive slot (NO pointer chase;
// addresses linear in j so loads pipeline): Tacc[spec] += gm[lm]*gm[24+l*4+n].
// Then LDS transpose (1 KB) and per-lane (n,c) expansion with emb, TP, K-MAJOR store.
__global__ __launch_bounds__(64) void kA_gather_tp(
    const float* __restrict__ emb, const int* __restrict__ species,
    const int* __restrict__ offsets, const int* __restrict__ counts,
    const int* __restrict__ bucket_s, const float* __restrict__ geomArr,
    float* __restrict__ feats, int N)
{
  __shared__ float Ts[256];
  int r = blockIdx.x;
  if (r >= N) return;
  int lane = threadIdx.x;
  int off = offsets[r], cnt = counts[r];
  // accumulation-phase roles
  int lma = lane>>2, na = lane&3;
  const int la = (lma==0)?0 : (lma<4)?1 : (lma<9)?2 : 3;
  float Tacc[4] = {0.0f,0.0f,0.0f,0.0f};
  for (int j=0; j<cnt; ++j){
    const float* gm = geomArr + (size_t)(off+j)*GSTRIDE;
    int spec = bucket_s[off+j]>>16;          // wave-uniform
    float v = gm[lma]*gm[24+la*4+na];
    Tacc[0] += (spec==0)? v : 0.0f;
    Tacc[1] += (spec==1)? v : 0.0f;
    Tacc[2] += (spec==2)? v : 0.0f;
    Tacc[3] += (spec==3)? v : 0.0f;
  }
  #pragma unroll
  for (int sp=0;sp<4;++sp) Ts[sp*64+lane] = Tacc[sp];
  // same-wave LDS RAW -> compiler lgkmcnt (single-wave block)
  // expansion-phase roles
  int n = lane>>4, c = lane&15;
  float f[16];
  #pragma unroll
  for (int lm=0; lm<16; ++lm){
    float acc = emb[0*NCH+c]*Ts[0*64+lm*4+n]
              + emb[1*NCH+c]*Ts[1*64+lm*4+n]
              + emb[2*NCH+c]*Ts[2*64+lm*4+n]
              + emb[3*NCH+c]*Ts[3*64+lm*4+n];
    f[lm] = 0.5f*acc;   // MP_SCALING
  }
  float g[16];
  g[0]=tp_row<0>(f);  g[1]=tp_row<1>(f);  g[2]=tp_row<2>(f);  g[3]=tp_row<3>(f);
  g[4]=tp_row<4>(f);  g[5]=tp_row<5>(f);  g[6]=tp_row<6>(f);  g[7]=tp_row<7>(f);
  g[8]=tp_row<8>(f);  g[9]=tp_row<9>(f);  g[10]=tp_row<10>(f); g[11]=tp_row<11>(f);
  g[12]=tp_row<12>(f); g[13]=tp_row<13>(f); g[14]=tp_row<14>(f); g[15]=tp_row<15>(f);
  float ek = emb[species[r]*NCH + c];
  float* fp = feats + (size_t)r*(LMDIM*KDIM) + lane*LMDIM;
  float4* fp4 = (float4*)fp;
  fp4[0] = make_float4((f[0]+g[0])*ek,  (f[1]+g[1])*ek,  (f[2]+g[2])*ek,  (f[3]+g[3])*ek);
  fp4[1] = make_float4((f[4]+g[4])*ek,  (f[5]+g[5])*ek,  (f[6]+g[6])*ek,  (f[7]+g[7])*ek);
  fp4[2] = make_float4((f[8]+g[8])*ek,  (f[9]+g[9])*ek,  (f[10]+g[10])*ek,(f[11]+g[11])*ek);
  fp4[3] = make_float4((f[12]+g[12])*ek,(f[13]+g[13])*ek,(f[14]+g[14])*ek,(f[15]+g[15])*ek);
}

// ---------------- kernel B: ONE-WAVE BLOCK per atom, K-MAJOR nb gather (R11 champion) ------
__global__ __launch_bounds__(64) void kB_mp2_mlp(
    const float* __restrict__ Weq,
    const float* __restrict__ W1, const float* __restrict__ W2,
    const float* __restrict__ wl,
    const int* __restrict__ offsets, const int* __restrict__ counts,
    const int* __restrict__ bucket_s, const float* __restrict__ geomArr,
    const float* __restrict__ embedded, float* __restrict__ eatom, int N)
{
  __shared__ __align__(16) float Arow[256];   // 1 KB/block
  int r = blockIdx.x;
  if (r >= N) return;
  int k = threadIdx.x;
  int off = offsets[r], cnt = counts[r];
  float Wq[4][8];
  #pragma unroll
  for (int L=0;L<4;++L)
    #pragma unroll
    for (int q=0;q<8;++q)
      Wq[L][q] = Weq[L*(NB*KDIM) + q*KDIM + k];
  float m[16];
  #pragma unroll
  for (int i=0;i<16;++i) m[i]=0.0f;

  float4 nb0c{}, nb1c{}, nb2c{}, nb3c{};
  {
    int pk0 = (cnt>0)? bucket_s[off] : 0;
    const float4* np0 = (const float4*)(embedded + (size_t)(pk0 & 0xFFFF)*(LMDIM*KDIM) + k*LMDIM);
    if (cnt>0){ nb0c=np0[0]; nb1c=np0[1]; nb2c=np0[2]; nb3c=np0[3]; }
  }
  for (int j=0; j<cnt; ++j){
    bool hn = (j+1<cnt);
    int pk_n = hn ? bucket_s[off+j+1] : 0;
    const float4* npn = (const float4*)(embedded + (size_t)(pk_n & 0xFFFF)*(LMDIM*KDIM) + k*LMDIM);
    float4 nb0n{}, nb1n{}, nb2n{}, nb3n{};
    if (hn){ nb0n=npn[0]; nb1n=npn[1]; nb2n=npn[2]; nb3n=npn[3]; }

    const float* gm = geomArr + (size_t)(off+j)*GSTRIDE;
    float4 s0 = *(const float4*)(gm+0);
    float4 s1 = *(const float4*)(gm+4);
    float4 s2 = *(const float4*)(gm+8);
    float4 s3 = *(const float4*)(gm+12);
    float4 b0 = *(const float4*)(gm+16);
    float4 b1 = *(const float4*)(gm+20);
    float sh[16] = {s0.x,s0.y,s0.z,s0.w, s1.x,s1.y,s1.z,s1.w,
                    s2.x,s2.y,s2.z,s2.w, s3.x,s3.y,s3.z,s3.w};
    float b[8] = {b0.x,b0.y,b0.z,b0.w, b1.x,b1.y,b1.z,b1.w};
    float Req[4];
    #pragma unroll
    for (int L=0;L<4;++L){
      float acc=0.0f;
      #pragma unroll
      for (int q=0;q<8;++q) acc += b[q]*Wq[L][q];
      Req[L]=acc;
    }
    #pragma unroll
    for (int q=0;q<4;++q){
      int ent = q*64 + k;
      const float4* c4 = (const float4*)CFLAT.v[ent];
      float4 c0=c4[0], c1=c4[1], c2=c4[2], c3=c4[3];
      float acc = c0.x*sh[0]+c0.y*sh[1]+c0.z*sh[2]+c0.w*sh[3]
                + c1.x*sh[4]+c1.y*sh[5]+c1.z*sh[6]+c1.w*sh[7]
                + c2.x*sh[8]+c2.y*sh[9]+c2.z*sh[10]+c2.w*sh[11]
                + c3.x*sh[12]+c3.y*sh[13]+c3.z*sh[14]+c3.w*sh[15];
      Arow[ent] = acc;
    }
    float nb_c[16] = {nb0c.x,nb0c.y,nb0c.z,nb0c.w, nb1c.x,nb1c.y,nb1c.z,nb1c.w,
                      nb2c.x,nb2c.y,nb2c.z,nb2c.w, nb3c.x,nb3c.y,nb3c.z,nb3c.w};
    #pragma unroll
    for (int M=0;M<16;++M){
      const int L = (M==0)?0 : (M<4)?1 : (M<9)?2 : 3;
      const float4* a4 = (const float4*)(Arow + M*16);
      float4 a0=a4[0], a1=a4[1], a2=a4[2], a3=a4[3];
      float acc = a0.x*nb_c[0]+a0.y*nb_c[1]+a0.z*nb_c[2]+a0.w*nb_c[3]
                + a1.x*nb_c[4]+a1.y*nb_c[5]+a1.z*nb_c[6]+a1.w*nb_c[7]
                + a2.x*nb_c[8]+a2.y*nb_c[9]+a2.z*nb_c[10]+a2.w*nb_c[11]
                + a3.x*nb_c[12]+a3.y*nb_c[13]+a3.z*nb_c[14]+a3.w*nb_c[15];
      m[M] += acc*Req[L];
    }
    nb0c=nb0n; nb1c=nb1n; nb2c=nb2n; nb3c=nb3n;
  }

  float inv = m[0];
  inv += inv_term<0>(m);
  inv += inv_term<1>(m);
  inv += inv_term<2>(m);
  inv += inv_term<3>(m);
  Arow[k] = inv;
  float a=0.0f;
  #pragma unroll
  for (int c=0;c<64;++c) a += Arow[c]*W1[c*64+k];
  a = a / (1.0f + expf(-a));           // silu
  Arow[64+k] = a;
  float h2=0.0f;
  #pragma unroll
  for (int c=0;c<64;++c) h2 += Arow[64+c]*W2[c*64+k];
  h2 = h2 / (1.0f + expf(-h2));
  float e = h2*wl[k];
  #pragma unroll
  for (int o=32; o>0; o>>=1) e += __shfl_down(e, o);
  if (k==0) eatom[r] = e;
}

__global__ __launch_bounds__(256) void k_reduce(const float* __restrict__ eatom,
                                                float* __restrict__ out, int N){
  __shared__ float buf[256];
  float a=0.0f;
  for (int i=threadIdx.x; i<N; i+=256) a += eatom[i];
  buf[threadIdx.x]=a;
  __syncthreads();
  #pragma unroll
  for (int o=128;o>0;o>>=1){
    if (threadIdx.x<o) buf[threadIdx.x]+=buf[threadIdx.x+o];
    __syncthreads();
  }
  if (threadIdx.x==0) out[0]=buf[0];
}

// ---------------- launch ----------------
extern "C" void kernel_launch(void* const* d_in, const int* in_sizes, int n_in,
                              void* d_out, int out_size, void* d_ws, size_t ws_size,
                              hipStream_t stream)
{
  const float* pos     = (const float*)d_in[0];
  const float* emb     = (const float*)d_in[1];
  const float* Winv    = (const float*)d_in[2];
  const float* Weq     = (const float*)d_in[3];
  const float* W1      = (const float*)d_in[4];
  const float* W2      = (const float*)d_in[5];
  const float* wl      = (const float*)d_in[6];
  const int*   species = (const int*)d_in[7];
  const int*   senders = (const int*)d_in[8];
  const int*   recv    = (const int*)d_in[9];
  int N = in_sizes[7];
  int E = in_sizes[8];

  char* ws = (char*)d_ws;
  float* feats   = (float*)ws;                                   // N*1024 f32, K-MAJOR
  float* geomArr = feats + (size_t)N*(LMDIM*KDIM);               // E*GSTRIDE f32 (worst case)
  float* eatom   = geomArr + (size_t)E*GSTRIDE;                  // N f32
  int*   counts  = (int*)(eatom + N);                            // N
  int*   cursor  = counts + N;                                   // N
  int*   offsets = cursor + N;                                   // N
  int*   bsum    = offsets + N;                                  // 256
  int*   bbase   = bsum + 256;                                   // 256
  int*   bucket_s= bbase + 256;                                  // E

  hipMemsetAsync(counts, 0, 2*(size_t)N*sizeof(int), stream);    // counts+cursor

  int ebl = (E+255)/256;
  int SB  = (N+255)/256;
  k_hist_d<<<ebl, 256, 0, stream>>>(pos, senders, recv, counts, E);
  k_scan1<<<SB, 256, 0, stream>>>(counts, offsets, bsum, N);
  k_scan2<<<1, 256, 0, stream>>>(bsum, bbase, SB);
  k_scan3<<<SB, 256, 0, stream>>>(offsets, bbase, N);
  k_geom<<<ebl, 256, 0, stream>>>(pos, Winv, species, senders, recv, offsets, cursor,
                                  bucket_s, geomArr, E);
  kA_gather_tp<<<N, 64, 0, stream>>>(emb, species, offsets, counts, bucket_s, geomArr, feats, N);
  kB_mp2_mlp<<<N, 64, 0, stream>>>(Weq, W1, W2, wl, offsets, counts, bucket_s, geomArr,
                                   feats, eatom, N);
  k_reduce<<<1, 256, 0, stream>>>(eatom, (float*)d_out, N);
}